// Round 2
// baseline (190.893 us; speedup 1.0000x reference)
//
#include <hip/hip_runtime.h>
#include <hip/hip_bf16.h>
#include <cmath>

#define H_ 128
#define W_ 128
#define HW_ 16384
#define C_ 64
#define N_ 8
#define BN_EPS 1e-5f

typedef __attribute__((ext_vector_type(8))) short short8;
typedef __attribute__((ext_vector_type(4))) float float4_;
typedef __attribute__((ext_vector_type(4))) unsigned uint4_;
typedef __attribute__((ext_vector_type(2))) unsigned uint2_;

__device__ inline short f2bf(float f) {
    unsigned u = __builtin_bit_cast(unsigned, f);
    u += 0x7fffu + ((u >> 16) & 1u);     // RNE
    return (short)(u >> 16);
}
__device__ inline float bf2f(short s) {
    unsigned u = ((unsigned)(unsigned short)s) << 16;
    return __builtin_bit_cast(float, u);
}
// packed RNE fp32x2 -> bf16x2 (v_cvt_pk_bf16_f32 on gfx950)
__device__ inline unsigned pkbf2(float a, float b) {
    __hip_bfloat162 h = __float22bfloat162_rn(make_float2(a, b));
    unsigned u;
    __builtin_memcpy(&u, &h, 4);
    return u;
}
__device__ inline float bperm_f(int addr, float v) {
    return __builtin_bit_cast(float,
        __builtin_amdgcn_ds_bpermute(addr, __builtin_bit_cast(int, v)));
}
__device__ inline float bfu_lo(unsigned u) {
    return __builtin_bit_cast(float, u << 16);
}
__device__ inline float bfu_hi(unsigned u) {
    return __builtin_bit_cast(float, u & 0xffff0000u);
}

#if __has_builtin(__builtin_amdgcn_fdot2_f32_bf16)
#define HAS_FDOT2 1
typedef __bf16 bf16x2v __attribute__((ext_vector_type(2)));
__device__ inline float fdot2bf(unsigned a, unsigned b, float c) {
    return __builtin_amdgcn_fdot2_f32_bf16(
        __builtin_bit_cast(bf16x2v, a), __builtin_bit_cast(bf16x2v, b), c, false);
}
#else
#define HAS_FDOT2 0
#endif

// ---- workspace layout (bytes) ----
#define XR8_OFS    0
#define WDEFB_OFS  16777216
#define BT27_OFS   16850944
#define BT9_OFS    16888320

// 16x8 tile: patch 12 rows x 20 cols per c8-plane.
// PS_*4 dw = 968, %32 = 8  -> consecutive c8 planes shift banks by 8 (as before)
#define PS_ 242

// ---------------- weight prep ----------------
__global__ __launch_bounds__(256) void prep_w(
    const float* __restrict__ w_off, const float* __restrict__ w_def,
    const float* __restrict__ w1, short* __restrict__ wdefB,
    short* __restrict__ bt27, short* __restrict__ bt9)
{
    int i = blockIdx.x * 256 + threadIdx.x;
    if (i < 36864) {
        int o = i / 576, r = i - o*576, t = r >> 6, c = r & 63;
        wdefB[i] = f2bf(w_def[o*576 + c*9 + t]);
    } else if (i < 36864 + 18688) {
        int j = i - 36864;
        int oc = j / 584, K = j - oc*584;
        float v = 0.f;
        if (oc < 27 && K < 576) { int t = K >> 6, c = K & 63; v = w_off[oc*576 + c*9 + t]; }
        bt27[j] = f2bf(v);
    } else if (i < 36864 + 18688 + 9344) {
        int j = i - 36864 - 18688;
        int oc = j / 584, K = j - oc*584;
        float v = 0.f;
        if (oc < 9 && K < 576) { int t = K >> 6, c = K & 63; v = w1[oc*576 + c*9 + t]; }
        bt9[j] = f2bf(v);
    }
}

// ======= fused: convert + conv27(offsets,filt) + deformable conv + residual ====
// 16x8 px tile, 256 thr (4 waves), one barrier. Grid (8,16,8)=1024 blocks
// -> 4 blocks/CU (was 512 blocks = 2/CU, grid-limited at 19.6% occupancy).
// Each wave owns 2 rows (was 4). LDS 31KB (fits 5/CU), VGPR cap 512/4=128.
__global__ __launch_bounds__(256, 4) void fused_off_deform(
    const float* __restrict__ x, const short8* __restrict__ btg27,
    const short8* __restrict__ wdefB, float* __restrict__ filt_out,
    short* __restrict__ xr8s)
{
    __shared__ short8 patch[8*PS_];     // [c8][py*20+px], 30,976 B
    const int tid = threadIdx.x;
    const int bx = blockIdx.x, by = blockIdx.y, n = blockIdx.z;
    const int lane = tid & 63, wid = tid >> 6;
    const int q = lane >> 4, col = lane & 15;
    const int r0 = by*8 - 2, c0 = bx*16 - 2;
    const float* xb = x + (size_t)n * C_ * HW_;

    // ---- stage 12x20 halo patch, fp32 -> bf16 (packed cvt), NC8HW8 in LDS ----
    for (int i = tid; i < 1920; i += 256) {
        int c8 = i / 240, r = i - c8*240;
        int py = r / 20, px = r - py*20;
        int gy = r0 + py, gx = c0 + px;
        uint4_ u = (uint4_){0u,0u,0u,0u};
        if ((unsigned)gy < 128u && (unsigned)gx < 128u) {
            const float* xp = xb + (size_t)(c8*8)*HW_ + gy*W_ + gx;
            u[0] = pkbf2(xp[0],      xp[HW_]);
            u[1] = pkbf2(xp[2*HW_],  xp[3*HW_]);
            u[2] = pkbf2(xp[4*HW_],  xp[5*HW_]);
            u[3] = pkbf2(xp[6*HW_],  xp[7*HW_]);
        }
        patch[c8*PS_ + py*20 + px] = __builtin_bit_cast(short8, u);
    }
    __syncthreads();

    // ---- conv27 phase (A=weights, B=patch) -> D[oc][pixel_col] ----
    float4_ a27[2][2];      // [oc-tile][row i]
    #pragma unroll
    for (int m = 0; m < 2; m++)
        #pragma unroll
        for (int i = 0; i < 2; i++) a27[m][i] = (float4_){0.f,0.f,0.f,0.f};

    #pragma unroll 2
    for (int k0 = 0; k0 < 18; k0++) {
        int t = k0 >> 1;
        int dy = t/3, dx = t - dy*3;
        int c8 = (k0 & 1)*4 + q;
        short8 w0 = btg27[col*73 + k0*4 + q];
        short8 w1 = btg27[(16 + col)*73 + k0*4 + q];
        #pragma unroll
        for (int i = 0; i < 2; i++) {
            int mt = wid*2 + i;
            short8 p = patch[c8*PS_ + (mt + dy + 1)*20 + (col + dx + 1)];
            a27[0][i] = __builtin_amdgcn_mfma_f32_16x16x32_bf16(w0, p, a27[0][i], 0,0,0);
            a27[1][i] = __builtin_amdgcn_mfma_f32_16x16x32_bf16(w1, p, a27[1][i], 0,0,0);
        }
    }

    // filt (oc 18..26) store: oc = 16 + q*4 + reg, pixel (row=wid*2+i, col)
    #pragma unroll
    for (int i = 0; i < 2; i++) {
        int prow = by*8 + wid*2 + i;
        #pragma unroll
        for (int reg = 0; reg < 4; reg++) {
            int oc = 16 + q*4 + reg;
            if (oc >= 18 && oc < 27)
                filt_out[((size_t)n*9 + (oc-18))*HW_ + prow*W_ + bx*16 + col] = a27[1][i][reg];
        }
    }

    // ---- deform phase: per wave 2 rows x 16 pixel_cols, N=64, K=576 ----
    float4_ acc[2][4];
    #pragma unroll
    for (int i = 0; i < 2; i++)
        #pragma unroll
        for (int nt = 0; nt < 4; nt++) acc[i][nt] = (float4_){0.f,0.f,0.f,0.f};

    const int col4 = col*4;
    const int gxc = bx*16 + col;

    // one tap of the deformable conv (afrag is LOCAL -> separate regs per call)
    auto tap = [&](int t, int dy, int dx, const float* oy, const float* ox) {
        short8 afrag[2][2];
        #pragma unroll
        for (int i = 0; i < 2; i++) {
            const int gy = by*8 + wid*2 + i;
            float py = (float)(gy + dy) + oy[i];
            float px = (float)(gxc + dx) + ox[i];
            float y0f = floorf(py), x0f = floorf(px);
            float wy1 = py - y0f, wx1 = px - x0f;
            float wy0 = 1.f - wy1, wx0 = 1.f - wx1;
            int y0 = (int)y0f, x0 = (int)x0f;
            int y1 = y0 + 1,   x1 = x0 + 1;
            float wy0v = ((unsigned)y0 < (unsigned)H_) ? wy0 : 0.f;
            float wy1v = ((unsigned)y1 < (unsigned)H_) ? wy1 : 0.f;
            float wx0v = ((unsigned)x0 < (unsigned)W_) ? wx0 : 0.f;
            float wx1v = ((unsigned)x1 < (unsigned)W_) ? wx1 : 0.f;
            float w00 = wy0v*wx0v, w01 = wy0v*wx1v;
            float w10 = wy1v*wx0v, w11 = wy1v*wx1v;
            int cy0 = min(max(y0, 0), H_-1), cy1 = min(max(y1, 0), H_-1);
            int cx0 = min(max(x0, 0), W_-1), cx1 = min(max(x1, 0), W_-1);
            int ly0 = cy0 - r0, ly1 = cy1 - r0;
            int lx0 = cx0 - c0, lx1 = cx1 - c0;
            bool inp = ((unsigned)ly0 < 12u) & ((unsigned)ly1 < 12u)
                     & ((unsigned)lx0 < 20u) & ((unsigned)lx1 < 20u);
#if HAS_FDOT2
            unsigned w01pk = pkbf2(w00, w01);
            unsigned w23pk = pkbf2(w10, w11);
#endif
            #pragma unroll
            for (int ks = 0; ks < 2; ks++) {
                const int c8 = ks*4 + q;
                uint4_ u;
                if (inp) {
                    const short8* pl = &patch[c8*PS_];
                    short8 p00 = pl[ly0*20 + lx0], p01 = pl[ly0*20 + lx1];
                    short8 p10 = pl[ly1*20 + lx0], p11 = pl[ly1*20 + lx1];
#if HAS_FDOT2
                    uint4_ u00 = __builtin_bit_cast(uint4_, p00);
                    uint4_ u01 = __builtin_bit_cast(uint4_, p01);
                    uint4_ u10 = __builtin_bit_cast(uint4_, p10);
                    uint4_ u11 = __builtin_bit_cast(uint4_, p11);
                    #pragma unroll
                    for (int d = 0; d < 4; d++) {
                        unsigned lo01 = __builtin_amdgcn_perm(u01[d], u00[d], 0x05040100u);
                        unsigned hi01 = __builtin_amdgcn_perm(u01[d], u00[d], 0x07060302u);
                        unsigned lo23 = __builtin_amdgcn_perm(u11[d], u10[d], 0x05040100u);
                        unsigned hi23 = __builtin_amdgcn_perm(u11[d], u10[d], 0x07060302u);
                        float slo = fdot2bf(lo01, w01pk, fdot2bf(lo23, w23pk, 0.f));
                        float shi = fdot2bf(hi01, w01pk, fdot2bf(hi23, w23pk, 0.f));
                        u[d] = pkbf2(slo, shi);
                    }
#else
                    float s[8];
                    #pragma unroll
                    for (int j = 0; j < 8; j++)
                        s[j] = bf2f(p00[j])*w00 + bf2f(p01[j])*w01
                             + bf2f(p10[j])*w10 + bf2f(p11[j])*w11;
                    u[0] = pkbf2(s[0],s[1]); u[1] = pkbf2(s[2],s[3]);
                    u[2] = pkbf2(s[4],s[5]); u[3] = pkbf2(s[6],s[7]);
#endif
                } else {
                    // rare (|off| >= ~1): exact global fp32 fallback
                    const float* xg = xb + (size_t)(c8*8)*HW_;
                    float s[8];
                    #pragma unroll
                    for (int j = 0; j < 8; j++) {
                        const float* xj = xg + (size_t)j*HW_;
                        s[j] = xj[cy0*W_+cx0]*w00 + xj[cy0*W_+cx1]*w01
                             + xj[cy1*W_+cx0]*w10 + xj[cy1*W_+cx1]*w11;
                    }
                    u[0] = pkbf2(s[0],s[1]); u[1] = pkbf2(s[2],s[3]);
                    u[2] = pkbf2(s[4],s[5]); u[3] = pkbf2(s[6],s[7]);
                }
                afrag[i][ks] = __builtin_bit_cast(short8, u);
            }
        }
        // swapped: A=weights, B=samples -> D[oc][pixel]
        #pragma unroll
        for (int ks = 0; ks < 2; ks++) {
            #pragma unroll
            for (int nt = 0; nt < 4; nt++) {
                short8 b = wdefB[(size_t)(nt*16 + col)*72 + t*8 + ks*4 + q];
                #pragma unroll
                for (int i = 0; i < 2; i++)
                    acc[i][nt] = __builtin_amdgcn_mfma_f32_16x16x32_bf16(
                        b, afrag[i][ks], acc[i][nt], 0,0,0);
            }
        }
    };

    // ---- tap t=8 first (offsets oc 16,17 live in a27[1] regs 0,1) ----
    {
        float oy8[2], ox8[2];
        #pragma unroll
        for (int i = 0; i < 2; i++) {
            oy8[i] = bperm_f(col4, a27[1][i][0]);
            ox8[i] = bperm_f(col4, a27[1][i][1]);
        }
        tap(8, 1, 1, oy8, ox8);      // a27[1] dead after this point
    }
    // ---- taps 0..7 in PAIRS (2tp, 2tp+1). Both taps of a pair share the
    // bpermute source lane (tp*16+col); regs {0,1} vs {2,3} are compile-time.
    // Separate afrag regs per tap body -> tap B's ds_reads overlap tap A's
    // blend + MFMA instead of stalling on the WAR hazard.
    #pragma unroll 1
    for (int tp = 0; tp < 4; tp++) {
        const int addr = (tp << 6) + col4;
        float oyA[2], oxA[2], oyB[2], oxB[2];
        #pragma unroll
        for (int i = 0; i < 2; i++) {
            oyA[i] = bperm_f(addr, a27[0][i][0]);
            oxA[i] = bperm_f(addr, a27[0][i][1]);
            oyB[i] = bperm_f(addr, a27[0][i][2]);
            oxB[i] = bperm_f(addr, a27[0][i][3]);
        }
        const int tA = 2*tp, tB = 2*tp + 1;
        tap(tA, tA/3 - 1, (tA - (tA/3)*3) - 1, oyA, oxA);
        tap(tB, tB/3 - 1, (tB - (tB/3)*3) - 1, oyB, oxB);
    }

    // ---- epilogue: lane holds 4 consecutive channels of pixel (row i, col) ----
    const short* ps = (const short*)patch;
    short* xout = xr8s + (size_t)n*8*HW_*8;
    const int inner = (q & 1) * 4;
    #pragma unroll
    for (int i = 0; i < 2; i++) {
        const int row = wid*2 + i;
        const int pix = (by*8 + row)*W_ + bx*16 + col;
        #pragma unroll
        for (int nt = 0; nt < 4; nt++) {
            const int c8 = 2*nt + (q >> 1);
            const unsigned* pw = (const unsigned*)(ps
                + ((c8*PS_ + (row+2)*20 + (col+2)) << 3) + inner);
            unsigned r0w = pw[0], r1w = pw[1];
            float v0 = acc[i][nt][0] + bfu_lo(r0w);
            float v1 = acc[i][nt][1] + bfu_hi(r0w);
            float v2 = acc[i][nt][2] + bfu_lo(r1w);
            float v3 = acc[i][nt][3] + bfu_hi(r1w);
            uint2_ o2 = (uint2_){ pkbf2(v0, v1), pkbf2(v2, v3) };
            *(uint2_*)(xout + (((size_t)c8*HW_ + pix) << 3) + inner) = o2;
        }
    }
}

// ---------------- conv9 + BN + ReLU (B direct from global, L1-hot) -----------
// 16x4 tile, grid (8,32,8)=2048 blocks -> 8 blocks/CU (was 512 = 2/CU).
// One row per wave, acc = one float4. LDS 14.6KB. launch_bounds(256,8)
// caps VGPR at 64 so 8 blocks are co-resident.
#define C9PS 114   // 6 rows x 18 cols = 108, pad to 114 (456 dw, %32 = 8)
__global__ __launch_bounds__(256, 8) void conv9_mfma(
    const short8* __restrict__ xr8, const short8* __restrict__ btg,
    const float* __restrict__ gamma, const float* __restrict__ beta,
    const float* __restrict__ mean, const float* __restrict__ var,
    float* __restrict__ out)
{
    __shared__ short8 patch[8*C9PS];
    const int tid = threadIdx.x;
    const int bx = blockIdx.x, by = blockIdx.y, n = blockIdx.z;

    for (int i = tid; i < 864; i += 256) {
        int c8 = i / 108, r = i - c8*108;
        int py = r / 18, px = r - py*18;
        int gy = by*4 - 1 + py, gx = bx*16 - 1 + px;
        short8 v = {0,0,0,0,0,0,0,0};
        if ((unsigned)gy < 128u && (unsigned)gx < 128u)
            v = xr8[(size_t)(n*8 + c8)*HW_ + gy*W_ + gx];
        patch[c8*C9PS + py*18 + px] = v;
    }
    __syncthreads();

    const int lane = tid & 63, wid = tid >> 6;
    const int q = lane >> 4, col = lane & 15;
    float4_ acc = (float4_){0.f,0.f,0.f,0.f};

    #pragma unroll 3
    for (int k0 = 0; k0 < 18; k0++) {
        int t = k0 >> 1;
        int dy = t/3, dx = t - dy*3;
        int c8 = (k0 & 1)*4 + q;
        short8 b0 = btg[col*73 + k0*4 + q];
        short8 a = patch[c8*C9PS + (wid + dy)*18 + (col + dx)];
        acc = __builtin_amdgcn_mfma_f32_16x16x32_bf16(a, b0, acc, 0,0,0);
    }

    if (col < 9) {
        float sc = gamma[col] * rsqrtf(var[col] + BN_EPS);
        float sh = beta[col] - mean[col] * sc;
        int pix0 = (by*4 + wid)*W_ + bx*16 + q*4;
        float4_ v;
        #pragma unroll
        for (int reg = 0; reg < 4; reg++)
            v[reg] = fmaxf(fmaf(acc[reg], sc, sh), 0.f);
        *(float4_*)&out[((size_t)n*9 + col)*HW_ + pix0] = v;
    }
}

extern "C" void kernel_launch(void* const* d_in, const int* in_sizes, int n_in,
                              void* d_out, int out_size, void* d_ws, size_t ws_size,
                              hipStream_t stream)
{
    const float* x     = (const float*)d_in[0];
    const float* w_off = (const float*)d_in[1];
    const float* w_def = (const float*)d_in[2];
    const float* w1    = (const float*)d_in[3];
    const float* gamma = (const float*)d_in[4];
    const float* beta  = (const float*)d_in[5];
    const float* mean  = (const float*)d_in[6];
    const float* var   = (const float*)d_in[7];
    float* out = (float*)d_out;

    char* ws = (char*)d_ws;
    short8* xr8     = (short8*)(ws + XR8_OFS);
    short*  wdefB   = (short*)(ws + WDEFB_OFS);
    short*  bt27    = (short*)(ws + BT27_OFS);
    short*  bt9     = (short*)(ws + BT9_OFS);

    float* h_out    = out;
    float* filt_out = out + (size_t)N_ * 9 * HW_;

    prep_w<<<dim3(254), dim3(256), 0, stream>>>(w_off, w_def, w1, wdefB, bt27, bt9);

    dim3 fgrid(8, 16, 8);
    fused_off_deform<<<fgrid, dim3(256), 0, stream>>>(
        x, (const short8*)bt27, (const short8*)wdefB, filt_out, (short*)xr8);
    dim3 c9grid(8, 32, 8);
    conv9_mfma<<<c9grid, dim3(256), 0, stream>>>(
        xr8, (const short8*)bt9, gamma, beta, mean, var, h_out);
}

// Round 3
// 171.761 us; speedup vs baseline: 1.1114x; 1.1114x over previous
//
#include <hip/hip_runtime.h>
#include <hip/hip_bf16.h>
#include <cmath>

#define H_ 128
#define W_ 128
#define HW_ 16384
#define C_ 64
#define N_ 8
#define BN_EPS 1e-5f

typedef __attribute__((ext_vector_type(8))) short short8;
typedef __attribute__((ext_vector_type(4))) float float4_;
typedef __attribute__((ext_vector_type(4))) unsigned uint4_;
typedef __attribute__((ext_vector_type(2))) unsigned uint2_;

__device__ inline short f2bf(float f) {
    unsigned u = __builtin_bit_cast(unsigned, f);
    u += 0x7fffu + ((u >> 16) & 1u);     // RNE
    return (short)(u >> 16);
}
__device__ inline float bf2f(short s) {
    unsigned u = ((unsigned)(unsigned short)s) << 16;
    return __builtin_bit_cast(float, u);
}
// packed RNE fp32x2 -> bf16x2 (v_cvt_pk_bf16_f32 on gfx950)
__device__ inline unsigned pkbf2(float a, float b) {
    __hip_bfloat162 h = __float22bfloat162_rn(make_float2(a, b));
    unsigned u;
    __builtin_memcpy(&u, &h, 4);
    return u;
}
__device__ inline float bperm_f(int addr, float v) {
    return __builtin_bit_cast(float,
        __builtin_amdgcn_ds_bpermute(addr, __builtin_bit_cast(int, v)));
}
__device__ inline float bfu_lo(unsigned u) {
    return __builtin_bit_cast(float, u << 16);
}
__device__ inline float bfu_hi(unsigned u) {
    return __builtin_bit_cast(float, u & 0xffff0000u);
}

#if __has_builtin(__builtin_amdgcn_fdot2_f32_bf16)
#define HAS_FDOT2 1
typedef __bf16 bf16x2v __attribute__((ext_vector_type(2)));
__device__ inline float fdot2bf(unsigned a, unsigned b, float c) {
    return __builtin_amdgcn_fdot2_f32_bf16(
        __builtin_bit_cast(bf16x2v, a), __builtin_bit_cast(bf16x2v, b), c, false);
}
#else
#define HAS_FDOT2 0
#endif

// ---- workspace layout (bytes) ----
#define XR8_OFS    0
#define WDEFB_OFS  16777216
#define BT27_OFS   16850944
#define BT9_OFS    16888320

// 16x8 tile: patch 12 rows x 20 cols per c8-plane.
// PS_*4 dw = 968, %32 = 8  -> consecutive c8 planes shift banks by 8 (as before)
#define PS_ 242

// ---------------- weight prep ----------------
__global__ __launch_bounds__(256) void prep_w(
    const float* __restrict__ w_off, const float* __restrict__ w_def,
    const float* __restrict__ w1, short* __restrict__ wdefB,
    short* __restrict__ bt27, short* __restrict__ bt9)
{
    int i = blockIdx.x * 256 + threadIdx.x;
    if (i < 36864) {
        int o = i / 576, r = i - o*576, t = r >> 6, c = r & 63;
        wdefB[i] = f2bf(w_def[o*576 + c*9 + t]);
    } else if (i < 36864 + 18688) {
        int j = i - 36864;
        int oc = j / 584, K = j - oc*584;
        float v = 0.f;
        if (oc < 27 && K < 576) { int t = K >> 6, c = K & 63; v = w_off[oc*576 + c*9 + t]; }
        bt27[j] = f2bf(v);
    } else if (i < 36864 + 18688 + 9344) {
        int j = i - 36864 - 18688;
        int oc = j / 584, K = j - oc*584;
        float v = 0.f;
        if (oc < 9 && K < 576) { int t = K >> 6, c = K & 63; v = w1[oc*576 + c*9 + t]; }
        bt9[j] = f2bf(v);
    }
}

// ======= fused: convert + conv27(offsets,filt) + deformable conv + residual ====
// 16x8 px tile, 256 thr (4 waves), one barrier. Grid (8,16,8)=1024 blocks
// -> 4 blocks/CU by grid. LDS 31KB (5/CU).
// launch_bounds(256,2): round-2's (256,4) drove the allocator to 64 VGPR and
// spilled ~68 MB/dispatch to scratch (WRITE_SIZE 21->90 MB). (256,2) is the
// proven-no-spill bound (round 0: 120 VGPR, zero scratch, with 2x this state);
// natural usage here ~100 <= 128 still admits 4 blocks/CU.
__global__ __launch_bounds__(256, 2) void fused_off_deform(
    const float* __restrict__ x, const short8* __restrict__ btg27,
    const short8* __restrict__ wdefB, float* __restrict__ filt_out,
    short* __restrict__ xr8s)
{
    __shared__ short8 patch[8*PS_];     // [c8][py*20+px], 30,976 B
    const int tid = threadIdx.x;
    const int bx = blockIdx.x, by = blockIdx.y, n = blockIdx.z;
    const int lane = tid & 63, wid = tid >> 6;
    const int q = lane >> 4, col = lane & 15;
    const int r0 = by*8 - 2, c0 = bx*16 - 2;
    const float* xb = x + (size_t)n * C_ * HW_;

    // ---- stage 12x20 halo patch, fp32 -> bf16 (packed cvt), NC8HW8 in LDS ----
    for (int i = tid; i < 1920; i += 256) {
        int c8 = i / 240, r = i - c8*240;
        int py = r / 20, px = r - py*20;
        int gy = r0 + py, gx = c0 + px;
        uint4_ u = (uint4_){0u,0u,0u,0u};
        if ((unsigned)gy < 128u && (unsigned)gx < 128u) {
            const float* xp = xb + (size_t)(c8*8)*HW_ + gy*W_ + gx;
            u[0] = pkbf2(xp[0],      xp[HW_]);
            u[1] = pkbf2(xp[2*HW_],  xp[3*HW_]);
            u[2] = pkbf2(xp[4*HW_],  xp[5*HW_]);
            u[3] = pkbf2(xp[6*HW_],  xp[7*HW_]);
        }
        patch[c8*PS_ + py*20 + px] = __builtin_bit_cast(short8, u);
    }
    __syncthreads();

    // ---- conv27 phase (A=weights, B=patch) -> D[oc][pixel_col] ----
    float4_ a27[2][2];      // [oc-tile][row i]
    #pragma unroll
    for (int m = 0; m < 2; m++)
        #pragma unroll
        for (int i = 0; i < 2; i++) a27[m][i] = (float4_){0.f,0.f,0.f,0.f};

    #pragma unroll 2
    for (int k0 = 0; k0 < 18; k0++) {
        int t = k0 >> 1;
        int dy = t/3, dx = t - dy*3;
        int c8 = (k0 & 1)*4 + q;
        short8 w0 = btg27[col*73 + k0*4 + q];
        short8 w1 = btg27[(16 + col)*73 + k0*4 + q];
        #pragma unroll
        for (int i = 0; i < 2; i++) {
            int mt = wid*2 + i;
            short8 p = patch[c8*PS_ + (mt + dy + 1)*20 + (col + dx + 1)];
            a27[0][i] = __builtin_amdgcn_mfma_f32_16x16x32_bf16(w0, p, a27[0][i], 0,0,0);
            a27[1][i] = __builtin_amdgcn_mfma_f32_16x16x32_bf16(w1, p, a27[1][i], 0,0,0);
        }
    }

    // filt (oc 18..26) store: oc = 16 + q*4 + reg, pixel (row=wid*2+i, col)
    #pragma unroll
    for (int i = 0; i < 2; i++) {
        int prow = by*8 + wid*2 + i;
        #pragma unroll
        for (int reg = 0; reg < 4; reg++) {
            int oc = 16 + q*4 + reg;
            if (oc >= 18 && oc < 27)
                filt_out[((size_t)n*9 + (oc-18))*HW_ + prow*W_ + bx*16 + col] = a27[1][i][reg];
        }
    }

    // ---- deform phase: per wave 2 rows x 16 pixel_cols, N=64, K=576 ----
    float4_ acc[2][4];
    #pragma unroll
    for (int i = 0; i < 2; i++)
        #pragma unroll
        for (int nt = 0; nt < 4; nt++) acc[i][nt] = (float4_){0.f,0.f,0.f,0.f};

    const int col4 = col*4;
    const int gxc = bx*16 + col;

    // one tap of the deformable conv (afrag is LOCAL -> separate regs per call)
    auto tap = [&](int t, int dy, int dx, const float* oy, const float* ox) {
        short8 afrag[2][2];
        #pragma unroll
        for (int i = 0; i < 2; i++) {
            const int gy = by*8 + wid*2 + i;
            float py = (float)(gy + dy) + oy[i];
            float px = (float)(gxc + dx) + ox[i];
            float y0f = floorf(py), x0f = floorf(px);
            float wy1 = py - y0f, wx1 = px - x0f;
            float wy0 = 1.f - wy1, wx0 = 1.f - wx1;
            int y0 = (int)y0f, x0 = (int)x0f;
            int y1 = y0 + 1,   x1 = x0 + 1;
            float wy0v = ((unsigned)y0 < (unsigned)H_) ? wy0 : 0.f;
            float wy1v = ((unsigned)y1 < (unsigned)H_) ? wy1 : 0.f;
            float wx0v = ((unsigned)x0 < (unsigned)W_) ? wx0 : 0.f;
            float wx1v = ((unsigned)x1 < (unsigned)W_) ? wx1 : 0.f;
            float w00 = wy0v*wx0v, w01 = wy0v*wx1v;
            float w10 = wy1v*wx0v, w11 = wy1v*wx1v;
            int cy0 = min(max(y0, 0), H_-1), cy1 = min(max(y1, 0), H_-1);
            int cx0 = min(max(x0, 0), W_-1), cx1 = min(max(x1, 0), W_-1);
            int ly0 = cy0 - r0, ly1 = cy1 - r0;
            int lx0 = cx0 - c0, lx1 = cx1 - c0;
            bool inp = ((unsigned)ly0 < 12u) & ((unsigned)ly1 < 12u)
                     & ((unsigned)lx0 < 20u) & ((unsigned)lx1 < 20u);
#if HAS_FDOT2
            unsigned w01pk = pkbf2(w00, w01);
            unsigned w23pk = pkbf2(w10, w11);
#endif
            #pragma unroll
            for (int ks = 0; ks < 2; ks++) {
                const int c8 = ks*4 + q;
                uint4_ u;
                if (inp) {
                    const short8* pl = &patch[c8*PS_];
                    short8 p00 = pl[ly0*20 + lx0], p01 = pl[ly0*20 + lx1];
                    short8 p10 = pl[ly1*20 + lx0], p11 = pl[ly1*20 + lx1];
#if HAS_FDOT2
                    uint4_ u00 = __builtin_bit_cast(uint4_, p00);
                    uint4_ u01 = __builtin_bit_cast(uint4_, p01);
                    uint4_ u10 = __builtin_bit_cast(uint4_, p10);
                    uint4_ u11 = __builtin_bit_cast(uint4_, p11);
                    #pragma unroll
                    for (int d = 0; d < 4; d++) {
                        unsigned lo01 = __builtin_amdgcn_perm(u01[d], u00[d], 0x05040100u);
                        unsigned hi01 = __builtin_amdgcn_perm(u01[d], u00[d], 0x07060302u);
                        unsigned lo23 = __builtin_amdgcn_perm(u11[d], u10[d], 0x05040100u);
                        unsigned hi23 = __builtin_amdgcn_perm(u11[d], u10[d], 0x07060302u);
                        float slo = fdot2bf(lo01, w01pk, fdot2bf(lo23, w23pk, 0.f));
                        float shi = fdot2bf(hi01, w01pk, fdot2bf(hi23, w23pk, 0.f));
                        u[d] = pkbf2(slo, shi);
                    }
#else
                    float s[8];
                    #pragma unroll
                    for (int j = 0; j < 8; j++)
                        s[j] = bf2f(p00[j])*w00 + bf2f(p01[j])*w01
                             + bf2f(p10[j])*w10 + bf2f(p11[j])*w11;
                    u[0] = pkbf2(s[0],s[1]); u[1] = pkbf2(s[2],s[3]);
                    u[2] = pkbf2(s[4],s[5]); u[3] = pkbf2(s[6],s[7]);
#endif
                } else {
                    // rare (|off| >= ~1): exact global fp32 fallback
                    const float* xg = xb + (size_t)(c8*8)*HW_;
                    float s[8];
                    #pragma unroll
                    for (int j = 0; j < 8; j++) {
                        const float* xj = xg + (size_t)j*HW_;
                        s[j] = xj[cy0*W_+cx0]*w00 + xj[cy0*W_+cx1]*w01
                             + xj[cy1*W_+cx0]*w10 + xj[cy1*W_+cx1]*w11;
                    }
                    u[0] = pkbf2(s[0],s[1]); u[1] = pkbf2(s[2],s[3]);
                    u[2] = pkbf2(s[4],s[5]); u[3] = pkbf2(s[6],s[7]);
                }
                afrag[i][ks] = __builtin_bit_cast(short8, u);
            }
        }
        // swapped: A=weights, B=samples -> D[oc][pixel]
        #pragma unroll
        for (int ks = 0; ks < 2; ks++) {
            #pragma unroll
            for (int nt = 0; nt < 4; nt++) {
                short8 b = wdefB[(size_t)(nt*16 + col)*72 + t*8 + ks*4 + q];
                #pragma unroll
                for (int i = 0; i < 2; i++)
                    acc[i][nt] = __builtin_amdgcn_mfma_f32_16x16x32_bf16(
                        b, afrag[i][ks], acc[i][nt], 0,0,0);
            }
        }
    };

    // ---- tap t=8 first (offsets oc 16,17 live in a27[1] regs 0,1) ----
    {
        float oy8[2], ox8[2];
        #pragma unroll
        for (int i = 0; i < 2; i++) {
            oy8[i] = bperm_f(col4, a27[1][i][0]);
            ox8[i] = bperm_f(col4, a27[1][i][1]);
        }
        tap(8, 1, 1, oy8, ox8);      // a27[1] dead after this point
    }
    // ---- taps 0..7 in PAIRS (2tp, 2tp+1). Both taps of a pair share the
    // bpermute source lane (tp*16+col); regs {0,1} vs {2,3} are compile-time.
    // Separate afrag regs per tap body -> tap B's ds_reads overlap tap A's
    // blend + MFMA instead of stalling on the WAR hazard.
    #pragma unroll 1
    for (int tp = 0; tp < 4; tp++) {
        const int addr = (tp << 6) + col4;
        float oyA[2], oxA[2], oyB[2], oxB[2];
        #pragma unroll
        for (int i = 0; i < 2; i++) {
            oyA[i] = bperm_f(addr, a27[0][i][0]);
            oxA[i] = bperm_f(addr, a27[0][i][1]);
            oyB[i] = bperm_f(addr, a27[0][i][2]);
            oxB[i] = bperm_f(addr, a27[0][i][3]);
        }
        const int tA = 2*tp, tB = 2*tp + 1;
        tap(tA, tA/3 - 1, (tA - (tA/3)*3) - 1, oyA, oxA);
        tap(tB, tB/3 - 1, (tB - (tB/3)*3) - 1, oyB, oxB);
    }

    // ---- epilogue: lane holds 4 consecutive channels of pixel (row i, col) ----
    const short* ps = (const short*)patch;
    short* xout = xr8s + (size_t)n*8*HW_*8;
    const int inner = (q & 1) * 4;
    #pragma unroll
    for (int i = 0; i < 2; i++) {
        const int row = wid*2 + i;
        const int pix = (by*8 + row)*W_ + bx*16 + col;
        #pragma unroll
        for (int nt = 0; nt < 4; nt++) {
            const int c8 = 2*nt + (q >> 1);
            const unsigned* pw = (const unsigned*)(ps
                + ((c8*PS_ + (row+2)*20 + (col+2)) << 3) + inner);
            unsigned r0w = pw[0], r1w = pw[1];
            float v0 = acc[i][nt][0] + bfu_lo(r0w);
            float v1 = acc[i][nt][1] + bfu_hi(r0w);
            float v2 = acc[i][nt][2] + bfu_lo(r1w);
            float v3 = acc[i][nt][3] + bfu_hi(r1w);
            uint2_ o2 = (uint2_){ pkbf2(v0, v1), pkbf2(v2, v3) };
            *(uint2_*)(xout + (((size_t)c8*HW_ + pix) << 3) + inner) = o2;
        }
    }
}

// ---------------- conv9 + BN + ReLU (B direct from global, L1-hot) -----------
// 16x4 tile, grid (8,32,8)=2048 blocks -> 8 blocks/CU. One row per wave,
// acc = one float4. LDS 14.6KB. ~5 us total; leave alone.
#define C9PS 114   // 6 rows x 18 cols = 108, pad to 114 (456 dw, %32 = 8)
__global__ __launch_bounds__(256, 8) void conv9_mfma(
    const short8* __restrict__ xr8, const short8* __restrict__ btg,
    const float* __restrict__ gamma, const float* __restrict__ beta,
    const float* __restrict__ mean, const float* __restrict__ var,
    float* __restrict__ out)
{
    __shared__ short8 patch[8*C9PS];
    const int tid = threadIdx.x;
    const int bx = blockIdx.x, by = blockIdx.y, n = blockIdx.z;

    for (int i = tid; i < 864; i += 256) {
        int c8 = i / 108, r = i - c8*108;
        int py = r / 18, px = r - py*18;
        int gy = by*4 - 1 + py, gx = bx*16 - 1 + px;
        short8 v = {0,0,0,0,0,0,0,0};
        if ((unsigned)gy < 128u && (unsigned)gx < 128u)
            v = xr8[(size_t)(n*8 + c8)*HW_ + gy*W_ + gx];
        patch[c8*C9PS + py*18 + px] = v;
    }
    __syncthreads();

    const int lane = tid & 63, wid = tid >> 6;
    const int q = lane >> 4, col = lane & 15;
    float4_ acc = (float4_){0.f,0.f,0.f,0.f};

    #pragma unroll 3
    for (int k0 = 0; k0 < 18; k0++) {
        int t = k0 >> 1;
        int dy = t/3, dx = t - dy*3;
        int c8 = (k0 & 1)*4 + q;
        short8 b0 = btg[col*73 + k0*4 + q];
        short8 a = patch[c8*C9PS + (wid + dy)*18 + (col + dx)];
        acc = __builtin_amdgcn_mfma_f32_16x16x32_bf16(a, b0, acc, 0,0,0);
    }

    if (col < 9) {
        float sc = gamma[col] * rsqrtf(var[col] + BN_EPS);
        float sh = beta[col] - mean[col] * sc;
        int pix0 = (by*4 + wid)*W_ + bx*16 + q*4;
        float4_ v;
        #pragma unroll
        for (int reg = 0; reg < 4; reg++)
            v[reg] = fmaxf(fmaf(acc[reg], sc, sh), 0.f);
        *(float4_*)&out[((size_t)n*9 + col)*HW_ + pix0] = v;
    }
}

extern "C" void kernel_launch(void* const* d_in, const int* in_sizes, int n_in,
                              void* d_out, int out_size, void* d_ws, size_t ws_size,
                              hipStream_t stream)
{
    const float* x     = (const float*)d_in[0];
    const float* w_off = (const float*)d_in[1];
    const float* w_def = (const float*)d_in[2];
    const float* w1    = (const float*)d_in[3];
    const float* gamma = (const float*)d_in[4];
    const float* beta  = (const float*)d_in[5];
    const float* mean  = (const float*)d_in[6];
    const float* var   = (const float*)d_in[7];
    float* out = (float*)d_out;

    char* ws = (char*)d_ws;
    short8* xr8     = (short8*)(ws + XR8_OFS);
    short*  wdefB   = (short*)(ws + WDEFB_OFS);
    short*  bt27    = (short*)(ws + BT27_OFS);
    short*  bt9     = (short*)(ws + BT9_OFS);

    float* h_out    = out;
    float* filt_out = out + (size_t)N_ * 9 * HW_;

    prep_w<<<dim3(254), dim3(256), 0, stream>>>(w_off, w_def, w1, wdefB, bt27, bt9);

    dim3 fgrid(8, 16, 8);
    fused_off_deform<<<fgrid, dim3(256), 0, stream>>>(
        x, (const short8*)bt27, (const short8*)wdefB, filt_out, (short*)xr8);
    dim3 c9grid(8, 32, 8);
    conv9_mfma<<<c9grid, dim3(256), 0, stream>>>(
        xr8, (const short8*)bt9, gamma, beta, mean, var, h_out);
}